// Round 5
// baseline (1339.805 us; speedup 1.0000x reference)
//
#include <hip/hip_runtime.h>
#include <stdint.h>

typedef unsigned short ushort_t;
typedef unsigned int uint_t;

#define H_SZ   1024
#define D_OUT  512
#define MAXN   64
#define MIDSP  512
#define MIDCD  512
#define MIDDEC 768

typedef __bf16 bf16x8 __attribute__((ext_vector_type(8)));
typedef float  f32x4  __attribute__((ext_vector_type(4)));

static __device__ __forceinline__ float asf(uint_t u) { union { uint_t i; float f; } c; c.i = u; return c.f; }
static __device__ __forceinline__ uint_t rnbf(float f) {            // fp32 -> bf16 (RNE), low 16 bits
  union { uint_t i; float f; } c; c.f = f;
  return (c.i + 0x7fffu + ((c.i >> 16) & 1u)) >> 16;
}
static __device__ __forceinline__ ushort_t f2bf(float f) { return (ushort_t)rnbf(f); }
static __device__ __forceinline__ uint_t mul2bf(uint_t a, uint_t b) {  // 2x packed bf16 multiply
  float a0 = asf(a << 16), a1 = asf(a & 0xffff0000u);
  float b0 = asf(b << 16), b1 = asf(b & 0xffff0000u);
  return rnbf(a0 * b0) | (rnbf(a1 * b1) << 16);
}
static __device__ __forceinline__ double mish_d(double x) { return x * tanh(log1p(exp(x))); }
static __device__ __forceinline__ float mish_f(float x) {
  // mish(x) = x*(t^2+2t)/(t^2+2t+2), t=e^x  (algebraic tanh(softplus))
  float t = __expf(x);
  float u = t * t + 2.f * t;
  float r = u / (u + 2.f);
  return (x > 30.f) ? x : x * r;
}

// ---------------- transpose + fp32->bf16 convert (dims multiples of 32) ----------------
__global__ __launch_bounds__(256) void k_transpose_cvt(const float* __restrict__ src,
                                                       ushort_t* __restrict__ dst, int R, int C) {
  __shared__ float tile[32][33];
  const int c0 = blockIdx.x * 32, r0 = blockIdx.y * 32;
  const int tc = threadIdx.x & 31, tr = threadIdx.x >> 5;
#pragma unroll
  for (int i = 0; i < 4; ++i) {
    const int r = tr + i * 8;
    tile[r][tc] = src[(size_t)(r0 + r) * C + (c0 + tc)];
  }
  __syncthreads();
#pragma unroll
  for (int i = 0; i < 4; ++i) {
    const int rr = tr + i * 8;
    dst[(size_t)(c0 + rr) * R + (r0 + tc)] = f2bf(tile[tc][rr]);
  }
}

// ---------------- key table fp32 -> bf16 ----------------
__global__ __launch_bounds__(256) void k_cvtkey(const float* __restrict__ src, ushort_t* __restrict__ dst) {
  const int i = blockIdx.x * 1024 + threadIdx.x;
#pragma unroll
  for (int j = 0; j < 4; ++j) dst[i + j * 256] = f2bf(src[i + j * 256]);
}

// ---------------- enc table: enc[v] = mish(v*cd_w1+cd_b1) @ cd_w2 + cd_b2 ----------------
__global__ __launch_bounds__(256) void k_enc(const float* __restrict__ w1, const float* __restrict__ b1,
                                             const float* __restrict__ w2, const float* __restrict__ b2,
                                             float* __restrict__ enc) {
  const int v = blockIdx.x, t = threadIdx.x;
  __shared__ float m[MIDCD];
  for (int i = t; i < MIDCD; i += 256) {
    double a = (double)v * (double)w1[i] + (double)b1[i];
    m[i] = (float)mish_d(a);
  }
  __syncthreads();
  for (int c = t; c < H_SZ; c += 256) {
    double s = (double)b2[c];
    for (int k = 0; k < MIDCD; ++k) s += (double)m[k] * (double)w2[(size_t)k * H_SZ + c];
    enc[(size_t)v * H_SZ + c] = (float)s;
  }
}

// ---------------- n-path: 8 rows per block; fp32 S accumulation, fp64 LN/mish/dot ----------------
__global__ __launch_bounds__(256) void k_npath(
    const float* __restrict__ z, const float* __restrict__ w1, const float* __restrict__ b1,
    const float* __restrict__ g, const float* __restrict__ be,
    const float* __restrict__ w2, const float* __restrict__ b2,
    const float* __restrict__ enc, int* __restrict__ nbuf,
    ushort_t* __restrict__ zc, float* __restrict__ outb) {
  const int t = threadIdx.x;
  const int r0 = blockIdx.x * 8;
  const int lane = t & 63, wv = t >> 6;
  __shared__ float zs[8][H_SZ];      // 32 KB
  __shared__ double wred[4];
  __shared__ int n8[8];

#pragma unroll
  for (int i = 0; i < 32; ++i) {
    const int idx = i * 256 + t;
    zs[idx >> 10][idx & 1023] = z[(size_t)r0 * H_SZ + idx];
  }
  __syncthreads();

  const int c0 = t, c1 = t + 256;
  float a0[8], a1[8];
#pragma unroll
  for (int r = 0; r < 8; ++r) { a0[r] = 0.f; a1[r] = 0.f; }

  for (int k = 0; k < H_SZ; k += 4) {
    float4 zr[8];
#pragma unroll
    for (int r = 0; r < 8; ++r) zr[r] = *(const float4*)&zs[r][k];
#pragma unroll
    for (int kk = 0; kk < 4; ++kk) {
      const float w0 = w1[(size_t)(k + kk) * MIDSP + c0];
      const float w1v = w1[(size_t)(k + kk) * MIDSP + c1];
#pragma unroll
      for (int r = 0; r < 8; ++r) {
        const float zk = ((const float*)&zr[r])[kk];
        a0[r] += zk * w0;
        a1[r] += zk * w1v;
      }
    }
  }

  auto block_sum = [&](double v) -> double {
#pragma unroll
    for (int off = 32; off > 0; off >>= 1) v += __shfl_down(v, off, 64);
    if (lane == 0) wred[wv] = v;
    __syncthreads();
    const double s = wred[0] + wred[1] + wred[2] + wred[3];
    __syncthreads();
    return s;
  };

  const double bia0 = (double)b1[c0], bia1 = (double)b1[c1];
  const double g0 = (double)g[c0], g1 = (double)g[c1];
  const double be0 = (double)be[c0], be1 = (double)be[c1];
  const double wv0 = (double)w2[c0], wv1 = (double)w2[c1];
  const double b2v = (double)b2[0];

  for (int r = 0; r < 8; ++r) {
    const double x0 = (double)a0[r] + bia0;
    const double x1 = (double)a1[r] + bia1;
    const double mu = block_sum(x0 + x1) * (1.0 / 512.0);
    const double varr = block_sum((x0 - mu) * (x0 - mu) + (x1 - mu) * (x1 - mu)) * (1.0 / 512.0);
    const double rs = 1.0 / sqrt(varr + 1e-5);
    const double h0 = mish_d((x0 - mu) * rs * g0 + be0);
    const double h1 = mish_d((x1 - mu) * rs * g1 + be1);
    const double logit = block_sum(h0 * wv0 + h1 * wv1) + b2v;
    if (t == 0) n8[r] = (int)fmin(64.0, fmax(0.0, rint(logit)));  // rint = half-to-even = np.round
  }
  __syncthreads();

  if (t < 8) nbuf[r0 + t] = n8[t];
#pragma unroll
  for (int i = 0; i < 2; ++i) {
    const int idx = i * 256 + t;
    const int r = idx >> 6, j = idx & 63;
    outb[(size_t)(r0 + r) * MAXN + j] = (j < n8[r]) ? (float)(r0 + r) : -1.0f;
  }
#pragma unroll
  for (int i = 0; i < 32; ++i) {
    const int idx = i * 256 + t;
    const int r = idx >> 10, c = idx & 1023;
    zc[(size_t)(r0 + r) * H_SZ + c] = f2bf(zs[r][c] - enc[(size_t)n8[r] * H_SZ + c]);
  }
}

// ---------------- fused decoder v2: one block per b, static 48KB LDS, 3 col-passes ----------------
// sA: double-buffered 64x64-K A stages, stride 128B, XOR-16B-chunk swizzle  -> 16 KB
// sT: 64 x 256-col bf16 slab, stride 512B, XOR swizzle                      -> 32 KB
__global__ __launch_bounds__(512, 2) void k_dec(
    const ushort_t* __restrict__ key, const ushort_t* __restrict__ w1t,
    const float* __restrict__ db1, const ushort_t* __restrict__ w2t,
    const float* __restrict__ db2, const ushort_t* __restrict__ zc,
    const int* __restrict__ nbuf, float* __restrict__ out) {
  __shared__ char sA[16384];
  __shared__ char sT[32768];

  const int tid = threadIdx.x;
  const int lane = tid & 63;
  const int w = tid >> 6;           // 8 waves
  const int q = lane >> 4;
  const int l15 = lane & 15;
  const int b = blockIdx.x;
  int n = nbuf[b];
  n = n < 0 ? 0 : (n > MAXN ? MAXN : n);   // defensive clamp
  const int JT = (n + 15) >> 4;            // live 16-row M-tiles (0..4), block-uniform

  const int gj = tid >> 3;          // A-gen row 0..63
  const int gk = tid & 7;           // 16B chunk within 64-col (128B) stage row
  const ushort_t* keyrow = key + (size_t)gj * H_SZ + gk * 8;
  const ushort_t* zrow = zc + (size_t)b * H_SZ + gk * 8;
  char* aw = sA + gj * 128 + ((gk ^ (gj & 7)) * 16);

  auto genA = [&](int s) {          // stage s covers k in [s*64, s*64+64)
    const int k0 = s * 64;
    uint4 kv = *(const uint4*)(keyrow + k0);
    uint4 zv = *(const uint4*)(zrow + k0);
    uint4 r;
    r.x = mul2bf(kv.x, zv.x); r.y = mul2bf(kv.y, zv.y);
    r.z = mul2bf(kv.z, zv.z); r.w = mul2bf(kv.w, zv.w);
    *(uint4*)(aw + (s & 1) * 8192) = r;
  };

  f32x4 z4 = {0.f, 0.f, 0.f, 0.f};
  f32x4 acc2[4][4];                 // X accumulator, persists across passes
#pragma unroll
  for (int mt = 0; mt < 4; ++mt)
#pragma unroll
    for (int i = 0; i < 4; ++i) acc2[mt][i] = z4;

  for (int p = 0; p < 3; ++p) {
    // ---- GEMM1 slab: T[:, p*256 .. p*256+256) ----
    f32x4 acc[4][2];
#pragma unroll
    for (int mt = 0; mt < 4; ++mt)
#pragma unroll
      for (int i = 0; i < 2; ++i) acc[mt][i] = z4;

    const ushort_t* bp1[2];
#pragma unroll
    for (int i = 0; i < 2; ++i)
      bp1[i] = w1t + (size_t)(p * 256 + (w * 2 + i) * 16 + l15) * H_SZ + q * 8;

    genA(0);
    __syncthreads();

    for (int s = 0; s < 16; ++s) {
      if (s < 15) genA(s + 1);
      const char* ab = sA + (s & 1) * 8192;
      const int kb = s * 64;
#pragma unroll
      for (int kk = 0; kk < 2; ++kk) {
        bf16x8 bfr[2];
#pragma unroll
        for (int i = 0; i < 2; ++i) bfr[i] = *(const bf16x8*)(bp1[i] + kb + kk * 32);
        bf16x8 afr[4];
#pragma unroll
        for (int mt = 0; mt < 4; ++mt)
          if (mt < JT)
            afr[mt] = *(const bf16x8*)(ab + (mt * 16 + l15) * 128 + (((kk * 4 + q) ^ (l15 & 7)) * 16));
#pragma unroll
        for (int mt = 0; mt < 4; ++mt)
          if (mt < JT)
#pragma unroll
            for (int i = 0; i < 2; ++i)
              acc[mt][i] = __builtin_amdgcn_mfma_f32_16x16x32_bf16(afr[mt], bfr[i], acc[mt][i], 0, 0, 0);
      }
      __syncthreads();
    }

    // ---- epilogue 1: +bias, mish, bf16 -> sT (XOR-swizzled 16B chunks) ----
#pragma unroll
    for (int mt = 0; mt < 4; ++mt)
      if (mt < JT)
#pragma unroll
        for (int i = 0; i < 2; ++i) {
          const int pl = (w * 2 + i) * 16 + l15;       // local col 0..255
          const float bias = db1[p * 256 + pl];
          const int c = pl >> 3;
          const int off = (pl & 7) * 2;
#pragma unroll
          for (int r = 0; r < 4; ++r) {
            const int j = mt * 16 + q * 4 + r;
            *(ushort_t*)(sT + j * 512 + ((c ^ (j & 7)) * 16 + off)) = f2bf(mish_f(acc[mt][i][r] + bias));
          }
        }
    __syncthreads();

    // ---- GEMM2 partial: acc2 += T-slab @ W2[k-slab, :] ----
    const ushort_t* bp2[4];
#pragma unroll
    for (int i = 0; i < 4; ++i)
      bp2[i] = w2t + (size_t)((w * 4 + i) * 16 + l15) * MIDDEC + p * 256 + q * 8;

    for (int ksl = 0; ksl < 8; ++ksl) {
      bf16x8 bfr[4];
#pragma unroll
      for (int i = 0; i < 4; ++i) bfr[i] = *(const bf16x8*)(bp2[i] + ksl * 32);
      bf16x8 afr[4];
#pragma unroll
      for (int mt = 0; mt < 4; ++mt)
        if (mt < JT) {
          const int j = mt * 16 + l15;
          const int c = ksl * 4 + q;
          afr[mt] = *(const bf16x8*)(sT + j * 512 + ((c ^ (j & 7)) * 16));
        }
#pragma unroll
      for (int mt = 0; mt < 4; ++mt)
        if (mt < JT)
#pragma unroll
          for (int i = 0; i < 4; ++i)
            acc2[mt][i] = __builtin_amdgcn_mfma_f32_16x16x32_bf16(afr[mt], bfr[i], acc2[mt][i], 0, 0, 0);
    }
    __syncthreads();   // sT reads done before next pass's epilogue overwrites
  }

  // ---- X epilogue + store, in 2 halves of 256 cols (sT holds one half) ----
  for (int h = 0; h < 2; ++h) {
    if ((w >> 2) == h) {             // waves owning cols [h*256, h*256+256)
#pragma unroll
      for (int mt = 0; mt < 4; ++mt)
        if (mt < JT)
#pragma unroll
          for (int i = 0; i < 4; ++i) {
            const int col = (w * 4 + i) * 16 + l15;    // global col, within this half
            const int cl = col & 255;
            const float bias = db2[col];
#pragma unroll
            for (int r = 0; r < 4; ++r) {
              const int j = mt * 16 + q * 4 + r;
              *(ushort_t*)(sT + j * 512 + cl * 2) = f2bf(acc2[mt][i][r] + bias);
            }
          }
    }
    __syncthreads();
    float* oh = out + (size_t)b * (MAXN * D_OUT) + h * 256;
#pragma unroll
    for (int it = 0; it < 4; ++it) {
      const int e = it * 4096 + tid * 8;   // 0..16383 within 64x256 half
      const int row = e >> 8, cl = e & 255;
      float4 v0 = make_float4(0.f, 0.f, 0.f, 0.f);
      float4 v1 = make_float4(0.f, 0.f, 0.f, 0.f);
      if (row < n) {
        const uint4 u = *(const uint4*)(sT + row * 512 + cl * 2);
        v0.x = asf(u.x << 16); v0.y = asf(u.x & 0xffff0000u);
        v0.z = asf(u.y << 16); v0.w = asf(u.y & 0xffff0000u);
        v1.x = asf(u.z << 16); v1.y = asf(u.z & 0xffff0000u);
        v1.z = asf(u.w << 16); v1.w = asf(u.w & 0xffff0000u);
      }
      *(float4*)(oh + (size_t)row * D_OUT + cl) = v0;
      *(float4*)(oh + (size_t)row * D_OUT + cl + 4) = v1;
    }
    __syncthreads();   // store reads done before h=1 epilogue overwrites sT
  }
}

// ---------------- launcher ----------------
extern "C" void kernel_launch(void* const* d_in, const int* in_sizes, int n_in,
                              void* d_out, int out_size, void* d_ws, size_t ws_size,
                              hipStream_t stream) {
  const float* z      = (const float*)d_in[0];
  const float* key    = (const float*)d_in[1];
  const float* sp_w1  = (const float*)d_in[2];
  const float* sp_b1  = (const float*)d_in[3];
  const float* sp_g   = (const float*)d_in[4];
  const float* sp_be  = (const float*)d_in[5];
  const float* sp_w2  = (const float*)d_in[6];
  const float* sp_b2  = (const float*)d_in[7];
  const float* cd_w1  = (const float*)d_in[8];
  const float* cd_b1  = (const float*)d_in[9];
  const float* cd_w2  = (const float*)d_in[10];
  const float* cd_b2  = (const float*)d_in[11];
  const float* dec_w1 = (const float*)d_in[12];
  const float* dec_b1 = (const float*)d_in[13];
  const float* dec_w2 = (const float*)d_in[14];
  const float* dec_b2 = (const float*)d_in[15];

  char* ws = (char*)d_ws;
  float*    enc   = (float*)(ws + 0);           // 65*1024*4   = 266,240
  int*      nbuf  = (int*)(ws + 266240);        // 2048*4      = 8,192
  ushort_t* zc    = (ushort_t*)(ws + 274432);   // 2048*1024*2 = 4,194,304
  ushort_t* w1t   = (ushort_t*)(ws + 4468736);  // 768*1024*2  = 1,572,864
  ushort_t* w2t   = (ushort_t*)(ws + 6041600);  // 512*768*2   = 786,432
  ushort_t* keyb  = (ushort_t*)(ws + 6828032);  // 64*1024*2   = 131,072

  float* out  = (float*)d_out;                           // x: 2048*64*512 fp32
  float* outb = out + (size_t)2048 * MAXN * D_OUT;       // batch: 2048*64 fp32

  (void)in_sizes; (void)n_in; (void)out_size; (void)ws_size;

  k_transpose_cvt<<<dim3(768 / 32, 1024 / 32), 256, 0, stream>>>(dec_w1, w1t, 1024, 768);
  k_transpose_cvt<<<dim3(512 / 32, 768 / 32), 256, 0, stream>>>(dec_w2, w2t, 768, 512);
  k_cvtkey<<<64, 256, 0, stream>>>(key, keyb);
  k_enc<<<65, 256, 0, stream>>>(cd_w1, cd_b1, cd_w2, cd_b2, enc);
  k_npath<<<256, 256, 0, stream>>>(z, sp_w1, sp_b1, sp_g, sp_be, sp_w2, sp_b2, enc, nbuf, zc, outb);
  k_dec<<<2048, 512, 0, stream>>>(keyb, w1t, dec_b1, w2t, dec_b2, zc, nbuf, out);
}